// Round 3
// baseline (451.084 us; speedup 1.0000x reference)
//
#include <hip/hip_runtime.h>
#include <math.h>

#define NQ 32768      // queue size (rows of A = Q^T)
#define NC 1000       // clusters (cols of A)
#define NC4 250       // float4s per row
#define NB 1024       // blocks for the big pass kernels
#define PSTRIDE 1024  // per-block partial row stride (floats)

__device__ __forceinline__ float wredsum(float v) {
#pragma unroll
    for (int off = 32; off > 0; off >>= 1) v += __shfl_xor(v, off, 64);
    return v;
}

// Separable Sinkhorn pass over A (read-only). E = exp(2*a).
// MODE 0: colacc[c] += E                       -> per-block partials
// MODE 1: t = sum_c E*s; r = 1/t; colacc += E*r -> per-block partials
// MODE 2: v = E*s; t = sum_c v; out = v/t       -> d_out (final, rows sum to 1)
template <int MODE>
__global__ __launch_bounds__(256) void k_pass(const float* __restrict__ in,
                                              const float* __restrict__ svec,
                                              float* __restrict__ outp) {
    __shared__ float sacc[NC];
    if (MODE < 2) {
        for (int i = threadIdx.x; i < NC; i += 256) sacc[i] = 0.f;
        __syncthreads();
    }
    const int lane = threadIdx.x & 63;
    const int nw = (gridDim.x * 256) >> 6;
    const int wave = (blockIdx.x * 256 + threadIdx.x) >> 6;

    float4 sf[4];
    if (MODE >= 1) {
        const float4* S4 = reinterpret_cast<const float4*>(svec);
#pragma unroll
        for (int k = 0; k < 4; ++k) {
            int c4 = k * 64 + lane;
            sf[k] = (c4 < NC4) ? S4[c4] : make_float4(0.f, 0.f, 0.f, 0.f);
        }
    }
    float acc[16];
    if (MODE < 2) {
#pragma unroll
        for (int i = 0; i < 16; ++i) acc[i] = 0.f;
    }

    // inactive lanes (k==3, lane>=58) keep nxt==0 -> e==1, weighted by sf==0
    float4 nxt[4];
#pragma unroll
    for (int k = 0; k < 4; ++k) nxt[k] = make_float4(0.f, 0.f, 0.f, 0.f);

    int row = wave;
    if (row < NQ) {
        const float4* rp = reinterpret_cast<const float4*>(in + (size_t)row * NC);
#pragma unroll
        for (int k = 0; k < 4; ++k) {
            int c4 = k * 64 + lane;
            if (c4 < NC4) nxt[k] = rp[c4];
        }
    }
    while (row < NQ) {
        float4 cur[4];
#pragma unroll
        for (int k = 0; k < 4; ++k) cur[k] = nxt[k];
        const int nrow = row + nw;
        if (nrow < NQ) {  // prefetch next row before compute
            const float4* rp = reinterpret_cast<const float4*>(in + (size_t)nrow * NC);
#pragma unroll
            for (int k = 0; k < 4; ++k) {
                int c4 = k * 64 + lane;
                if (c4 < NC4) nxt[k] = rp[c4];
            }
        }
        float4 e[4];
#pragma unroll
        for (int k = 0; k < 4; ++k) {
            e[k].x = __expf(2.f * cur[k].x);
            e[k].y = __expf(2.f * cur[k].y);
            e[k].z = __expf(2.f * cur[k].z);
            e[k].w = __expf(2.f * cur[k].w);
        }
        if (MODE == 0) {
#pragma unroll
            for (int k = 0; k < 4; ++k) {
                acc[4 * k + 0] += e[k].x; acc[4 * k + 1] += e[k].y;
                acc[4 * k + 2] += e[k].z; acc[4 * k + 3] += e[k].w;
            }
        } else {
            float t = 0.f;
#pragma unroll
            for (int k = 0; k < 4; ++k) {
                t += e[k].x * sf[k].x + e[k].y * sf[k].y
                   + e[k].z * sf[k].z + e[k].w * sf[k].w;
            }
            t = wredsum(t);
            const float r = 1.0f / t;
            if (MODE == 1) {
#pragma unroll
                for (int k = 0; k < 4; ++k) {
                    acc[4 * k + 0] += e[k].x * r; acc[4 * k + 1] += e[k].y * r;
                    acc[4 * k + 2] += e[k].z * r; acc[4 * k + 3] += e[k].w * r;
                }
            } else {
                float4* op = reinterpret_cast<float4*>(outp + (size_t)row * NC);
#pragma unroll
                for (int k = 0; k < 4; ++k) {
                    int c4 = k * 64 + lane;
                    if (c4 < NC4) {
                        op[c4] = make_float4(e[k].x * sf[k].x * r,
                                             e[k].y * sf[k].y * r,
                                             e[k].z * sf[k].z * r,
                                             e[k].w * sf[k].w * r);
                    }
                }
            }
        }
        row = nrow;
    }
    if (MODE < 2) {
#pragma unroll
        for (int k = 0; k < 4; ++k) {
            int c4 = k * 64 + lane;
            if (c4 < NC4) {
                atomicAdd(&sacc[4 * c4 + 0], acc[4 * k + 0]);
                atomicAdd(&sacc[4 * c4 + 1], acc[4 * k + 1]);
                atomicAdd(&sacc[4 * c4 + 2], acc[4 * k + 2]);
                atomicAdd(&sacc[4 * c4 + 3], acc[4 * k + 3]);
            }
        }
        __syncthreads();
        float* prow = outp + (size_t)blockIdx.x * PSTRIDE;
        for (int i = threadIdx.x; i < NC; i += 256) prow[i] = sacc[i];
    }
}

// Reduce per-block partials -> G. grid 32: (b&7)=c-chunk of 128, (b>>3)=p-chunk of 256.
__global__ __launch_bounds__(128) void k_reduceG(const float* __restrict__ part,
                                                 float* __restrict__ G) {
    const int c = (blockIdx.x & 7) * 128 + threadIdx.x;
    const int p0 = (blockIdx.x >> 3) * 256;
    if (c < NC) {
        float sum = 0.f;
        for (int p = p0; p < p0 + 256; p += 4) {
            sum += part[(size_t)p * PSTRIDE + c]
                 + part[(size_t)(p + 1) * PSTRIDE + c]
                 + part[(size_t)(p + 2) * PSTRIDE + c]
                 + part[(size_t)(p + 3) * PSTRIDE + c];
        }
        atomicAdd(&G[c], sum);  // only 4 adds per address
    }
}

// Stable descending rank of G0; K = softmax(w*log(sigmoid(k))); s1 = K[rank]/G0.
__global__ __launch_bounds__(128) void k_rank(const float* __restrict__ G,
                                              const float* __restrict__ learn_k,
                                              float* __restrict__ Ksc,
                                              float* __restrict__ svec) {
    __shared__ float sS[NC];
    __shared__ float sred[2];
    for (int i = threadIdx.x; i < NC; i += 128) sS[i] = G[i];
    const float L = -log1pf(expf(-learn_k[0]));  // log(sigmoid(k)) <= 0
    float part = 0.f;
    for (int i = threadIdx.x; i < NC; i += 128)
        part += expf((float)i * (1.0f / 999.0f) * L);
    part = wredsum(part);
    if ((threadIdx.x & 63) == 0) sred[threadIdx.x >> 6] = part;
    __syncthreads();
    const float denom = sred[0] + sred[1];
    const int c = blockIdx.x * 128 + threadIdx.x;
    if (c < NC) {
        const float sc = sS[c];
        int p = 0;
#pragma unroll 4
        for (int j = 0; j < NC; ++j) {
            float sj = sS[j];
            p += (sj > sc) || (sj == sc && j < c);  // stable descending rank
        }
        const float ks = expf((float)p * (1.0f / 999.0f) * L) / denom;
        Ksc[c] = ks;
        svec[c] = ks / sc;
    }
}

__global__ __launch_bounds__(256) void k_prepS(const float* __restrict__ Ksc,
                                               const float* __restrict__ G,
                                               float* __restrict__ svec) {
    const int i = blockIdx.x * 256 + threadIdx.x;
    if (i < NC) svec[i] = Ksc[i] / G[i];
}

extern "C" void kernel_launch(void* const* d_in, const int* in_sizes, int n_in,
                              void* d_out, int out_size, void* d_ws, size_t ws_size,
                              hipStream_t stream) {
    const float* A = (const float*)d_in[0];
    const float* lk = (const float*)d_in[1];
    float* out = (float*)d_out;
    float* ws = (float*)d_ws;
    float* G0 = ws;            // [1024]
    float* G1 = ws + 1024;
    float* G2 = ws + 2048;
    float* Ksc = ws + 3072;
    float* sv = ws + 4096;
    float* part = ws + 8192;   // [1024][1024]

    hipMemsetAsync(ws, 0, 3072 * sizeof(float), stream);  // zero G0,G1,G2

    k_pass<0><<<NB, 256, 0, stream>>>(A, nullptr, part);
    k_reduceG<<<32, 128, 0, stream>>>(part, G0);
    k_rank<<<8, 128, 0, stream>>>(G0, lk, Ksc, sv);
    k_pass<1><<<NB, 256, 0, stream>>>(A, sv, part);
    k_reduceG<<<32, 128, 0, stream>>>(part, G1);
    k_prepS<<<4, 256, 0, stream>>>(Ksc, G1, sv);
    k_pass<1><<<NB, 256, 0, stream>>>(A, sv, part);
    k_reduceG<<<32, 128, 0, stream>>>(part, G2);
    k_prepS<<<4, 256, 0, stream>>>(Ksc, G2, sv);
    k_pass<2><<<NB, 256, 0, stream>>>(A, sv, out);
}